// Round 1
// baseline (806.246 us; speedup 1.0000x reference)
//
#include <hip/hip_runtime.h>
#include <hip/hip_fp16.h>
#include <hip/hip_bf16.h>

// Problem constants
constexpr int DN = 128, DE = 64, DG = 32, DO = 128;
constexpr int K1 = DN + DE + DG;  // 224
constexpr float NEG_SLOPE = 0.01f;
constexpr float LN_EPS = 1e-5f;

constexpr int EPB = 128;   // edges per block (4 waves x 32 edges)
constexpr int NB  = 64;    // nodes per block (4 waves x 16 nodes)
constexpr int T_LD = 136;  // node per-wave LDS row stride in shorts (272B)
constexpr int H_LD = 132;  // edge h-tile LDS row stride in halves (264B -> rows 8 banks apart per quad)

typedef __attribute__((ext_vector_type(8))) short bf16x8;
typedef __attribute__((ext_vector_type(4))) float f32x4;

__device__ inline unsigned short f2bf(float f) {
    unsigned u = __builtin_bit_cast(unsigned, f);
    u += 0x7FFFu + ((u >> 16) & 1u);
    return (unsigned short)(u >> 16);
}

__device__ inline bf16x8 pk8(float4 p, float4 q) {
    bf16x8 r;
    r[0] = (short)f2bf(p.x); r[1] = (short)f2bf(p.y);
    r[2] = (short)f2bf(p.z); r[3] = (short)f2bf(p.w);
    r[4] = (short)f2bf(q.x); r[5] = (short)f2bf(q.y);
    r[6] = (short)f2bf(q.z); r[7] = (short)f2bf(q.w);
    return r;
}

// ---------------------------------------------------------------------------
// Weight prep. Fragment-ordered bf16 tables, B-frag layout for
// mfma_f32_16x16x32_bf16: B[n = nt*16+(lane&15)][k = ks*32+(lane>>4)*8+j].
// Slab-sets (512 frag-lanes each):
//   [0,7)  W1a            (K=224)
//   [7,11) W2a rows 0..127 (x part of concat)
//   [11,15) Wc = W1b @ W2a[128:256,:]   (folded: agg GEMM eliminated)
//   [15,19) W2b
// Extra 128 threads compute bc[n] = b1b @ W2a[128:256,:].
// ---------------------------------------------------------------------------
__global__ void wprep_kernel(const float* __restrict__ W1a,
                             const float* __restrict__ W1b,
                             const float* __restrict__ W2a,
                             const float* __restrict__ W2b,
                             const float* __restrict__ b1b,
                             unsigned short* __restrict__ tab,
                             float* __restrict__ bc) {
    int idx = blockIdx.x * 256 + threadIdx.x;
    if (idx >= 19 * 512 + 128) return;
    if (idx >= 19 * 512) {                 // bc = b1b @ W2a_bot
        int n = idx - 19 * 512;
        float s = 0.f;
        for (int j = 0; j < DO; ++j) s += b1b[j] * W2a[(long)(DN + j) * DO + n];
        bc[n] = s;
        return;
    }
    int slabset = idx >> 9;
    int rem = idx & 511;
    int nt = rem >> 6, lane = rem & 63;
    int quad = lane >> 4, l15 = lane & 15;
    int n = nt * 16 + l15;
    union { ushort4 u4[2]; unsigned short s[8]; } o;
    if (slabset < 7) {
        int k0 = slabset * 32 + quad * 8;
#pragma unroll
        for (int j = 0; j < 8; ++j) o.s[j] = f2bf(W1a[(long)(k0 + j) * DO + n]);
    } else if (slabset < 11) {
        int k0 = (slabset - 7) * 32 + quad * 8;
#pragma unroll
        for (int j = 0; j < 8; ++j) o.s[j] = f2bf(W2a[(long)(k0 + j) * DO + n]);
    } else if (slabset < 15) {
        int k0 = (slabset - 11) * 32 + quad * 8;
        float s[8] = {0.f, 0.f, 0.f, 0.f, 0.f, 0.f, 0.f, 0.f};
        for (int j2 = 0; j2 < DO; ++j2) {
            float wa = W2a[(long)(DN + j2) * DO + n];
#pragma unroll
            for (int j = 0; j < 8; ++j) s[j] += W1b[(long)(k0 + j) * DO + j2] * wa;
        }
#pragma unroll
        for (int j = 0; j < 8; ++j) o.s[j] = f2bf(s[j]);
    } else {
        int k0 = (slabset - 15) * 32 + quad * 8;
#pragma unroll
        for (int j = 0; j < 8; ++j) o.s[j] = f2bf(W2b[(long)(k0 + j) * DO + n]);
    }
    *(ushort4*)&tab[(long)idx * 8]     = o.u4[0];
    *(ushort4*)&tab[(long)idx * 8 + 4] = o.u4[1];
}

// ---------------------------------------------------------------------------
// CSR build: histogram by dest -> exclusive scan -> slot scatter.
// ---------------------------------------------------------------------------
__global__ void hist_kernel(const int* __restrict__ edge_index,
                            int* __restrict__ counts, int E) {
    int e = blockIdx.x * 256 + threadIdx.x;
    if (e < E) atomicAdd(&counts[edge_index[E + e]], 1);
}

__global__ __launch_bounds__(1024) void scan_kernel(
    const int* __restrict__ counts, int* __restrict__ offsets,
    int* __restrict__ cursor, int N) {
    __shared__ int s_ws[16];
    __shared__ int s_carry;
    const int tid = threadIdx.x, lane = tid & 63, wv = tid >> 6;
    if (tid == 0) s_carry = 0;
    __syncthreads();
    for (int base = 0; base < N; base += 1024) {
        int i = base + tid;
        int v = (i < N) ? counts[i] : 0;
        int s = v;
#pragma unroll
        for (int off = 1; off < 64; off <<= 1) {
            int t = __shfl_up(s, off, 64);
            if (lane >= off) s += t;
        }
        if (lane == 63) s_ws[wv] = s;
        __syncthreads();
        if (tid < 16) {
            int w = s_ws[tid];
#pragma unroll
            for (int off = 1; off < 16; off <<= 1) {
                int t = __shfl_up(w, off, 16);
                if (tid >= off) w += t;
            }
            s_ws[tid] = w;
        }
        __syncthreads();
        int carry = s_carry;
        int woff = (wv == 0) ? 0 : s_ws[wv - 1];
        int excl = carry + woff + (s - v);
        if (i < N) { offsets[i] = excl; cursor[i] = excl; }
        int total = s_ws[15];
        __syncthreads();
        if (tid == 0) s_carry = carry + total;
        __syncthreads();
    }
    if (threadIdx.x == 0) offsets[N] = s_carry;   // == E
}

__global__ void scatter_kernel(const int* __restrict__ edge_index,
                               int* __restrict__ cursor,
                               int2* __restrict__ sorted, int E) {
    int e = blockIdx.x * 256 + threadIdx.x;
    if (e < E) {
        int d = edge_index[E + e];
        int pos = atomicAdd(&cursor[d], 1);
        sorted[pos] = make_int2(e, d);
    }
}

// ---------------------------------------------------------------------------
// Edge kernel over DEST-SORTED edges:
//   h1 = concat(x[src], edge_attr, u) @ W1a  (register-direct bf16 MFMA)
//   h  = LN(leaky(h1+b1a)); h -> f16 LDS tile; block-level run-reduction in
//   f32; ~1 coalesced f32 atomic per dest-run per dim into sums (f32, d_out).
// Replaces 51.2M packed-f16 scatter atomics with ~8M coalesced f32 atomics.
// ---------------------------------------------------------------------------
__global__ __launch_bounds__(256) void edge_kernel(
    const float* __restrict__ x, const int* __restrict__ edge_index,
    const float* __restrict__ edge_attr, const float* __restrict__ u,
    const int2* __restrict__ sorted, const unsigned short* __restrict__ tab,
    const float* __restrict__ b1a, const float* __restrict__ g1,
    const float* __restrict__ be1,
    float* __restrict__ sums, int E)
{
    __shared__ int s_src[EPB], s_eid[EPB], s_dst[EPB];
    __shared__ alignas(16) __half s_h[EPB * H_LD];   // 33.8 KB

    const int tid = threadIdx.x, lane = tid & 63, wave = tid >> 6;
    const int l15 = lane & 15, quad = lane >> 4;
    const int ebase = blockIdx.x * EPB;
    const int evalid = min(EPB, E - ebase);

    if (tid < EPB) {
        bool v = tid < evalid;
        int2 ed = v ? sorted[ebase + tid] : make_int2(0, 0);
        s_eid[tid] = ed.x;
        s_dst[tid] = ed.y;
        s_src[tid] = edge_index[ed.x];
    }
    __syncthreads();

    const int r0 = wave * 32 + l15, r1 = r0 + 16;
    const long xs0 = (long)s_src[r0] * DN;
    const long xs1 = (long)s_src[r1] * DN;
    const long er0 = (long)s_eid[r0] * DE;
    const long er1 = (long)s_eid[r1] * DE;
    const bf16x8* tW1a = (const bf16x8*)tab;   // slab-sets 0..6
    const int kq = quad * 8;

    f32x4 acc[2][8];
#pragma unroll
    for (int mt = 0; mt < 2; ++mt)
#pragma unroll
        for (int nt = 0; nt < 8; ++nt) acc[mt][nt] = (f32x4){0.f, 0.f, 0.f, 0.f};

#pragma unroll
    for (int ks = 0; ks < 7; ++ks) {
        float4 p0, q0, p1, q1;
        if (ks < 4) {
            const float* b0 = &x[xs0 + ks * 32 + kq];
            const float* b1 = &x[xs1 + ks * 32 + kq];
            p0 = *(const float4*)b0; q0 = *(const float4*)(b0 + 4);
            p1 = *(const float4*)b1; q1 = *(const float4*)(b1 + 4);
        } else if (ks < 6) {
            int c = ks * 32 - DN + kq;
            const float* b0 = &edge_attr[er0 + c];
            const float* b1 = &edge_attr[er1 + c];
            p0 = *(const float4*)b0; q0 = *(const float4*)(b0 + 4);
            p1 = *(const float4*)b1; q1 = *(const float4*)(b1 + 4);
        } else {
            p0 = *(const float4*)&u[kq]; q0 = *(const float4*)&u[kq + 4];
            p1 = p0; q1 = q0;
        }
        bf16x8 a0 = pk8(p0, q0);
        bf16x8 a1 = pk8(p1, q1);
#pragma unroll
        for (int nt = 0; nt < 8; ++nt) {
            bf16x8 b = tW1a[(ks * 8 + nt) * 64 + lane];
            acc[0][nt] = __builtin_amdgcn_mfma_f32_16x16x32_bf16(a0, b, acc[0][nt], 0, 0, 0);
            acc[1][nt] = __builtin_amdgcn_mfma_f32_16x16x32_bf16(a1, b, acc[1][nt], 0, 0, 0);
        }
    }

    // bias + LeakyReLU + LayerNorm -> f16 LDS tile
    float ba[8], gg[8], bb[8];
#pragma unroll
    for (int nt = 0; nt < 8; ++nt) {
        int col = nt * 16 + l15;
        ba[nt] = b1a[col]; gg[nt] = g1[col]; bb[nt] = be1[col];
    }
#pragma unroll
    for (int mt = 0; mt < 2; ++mt) {
#pragma unroll
        for (int r = 0; r < 4; ++r) {
            float v[8];
            float s = 0.f, q = 0.f;
#pragma unroll
            for (int nt = 0; nt < 8; ++nt) {
                float t = acc[mt][nt][r] + ba[nt];
                t = (t >= 0.f) ? t : NEG_SLOPE * t;
                v[nt] = t; s += t; q += t * t;
            }
#pragma unroll
            for (int off = 1; off < 16; off <<= 1) {
                s += __shfl_xor(s, off, 64);
                q += __shfl_xor(q, off, 64);
            }
            float mu  = s * (1.f / DO);
            float var = q * (1.f / DO) - mu * mu;
            float rs  = rsqrtf(var + LN_EPS);
            int lrow = wave * 32 + mt * 16 + quad * 4 + r;
#pragma unroll
            for (int nt = 0; nt < 8; ++nt) {
                float h  = (v[nt] - mu) * rs * gg[nt] + bb[nt];
                float hp = __shfl_xor(h, 1, 64);
                if ((l15 & 1) == 0) {
                    *(__half2*)&s_h[lrow * H_LD + nt * 16 + l15] =
                        __halves2half2(__float2half_rn(h), __float2half_rn(hp));
                }
            }
        }
    }
    __syncthreads();

    // run-reduction: 2 groups of 128 threads; thread owns dim d, walks its
    // half of the (sorted) edge tile, flushes one f32 atomic per dest-run.
    {
        const int d = tid & 127, g = tid >> 7;
        int e0 = g * 64, e1 = min(e0 + 64, evalid);
        if (e0 < e1) {
            float accv = 0.f;
            int cur = s_dst[e0];
            for (int e = e0; e < e1; ++e) {
                int dd = s_dst[e];          // uniform across the group
                if (dd != cur) {
                    atomicAdd(&sums[(long)cur * DO + d], accv);
                    accv = 0.f; cur = dd;
                }
                accv += __half2float(s_h[e * H_LD + d]);
            }
            atomicAdd(&sums[(long)cur * DO + d], accv);
        }
    }
}

// ---------------------------------------------------------------------------
// Node kernel (GEMM0 folded away via Wc = W1b@W2a_bot):
//   pre = x @ W2a_top + (sums/max(cnt,1)) @ Wc + b2a + (cnt>0)*bc
//   out = LN(leaky(pre)) @ W2b + b2b
// cnt comes from CSR offsets (no cnt array). sums lives in d_out (f32);
// each block reads only its own node slice before overwriting it with out.
// ---------------------------------------------------------------------------
__global__ __launch_bounds__(256) void node_kernel(
    const float* __restrict__ x, const float* __restrict__ sums,
    const int* __restrict__ offsets, const unsigned short* __restrict__ tab,
    const float* __restrict__ bc,
    const float* __restrict__ b2a, const float* __restrict__ g2,
    const float* __restrict__ be2, const float* __restrict__ b2b,
    float* __restrict__ out, int N)
{
    __shared__ unsigned short s_t[4][16 * T_LD];  // per-wave [16 rows][128 cols]

    const int tid = threadIdx.x, lane = tid & 63, wave = tid >> 6;
    const int l15 = lane & 15, quad = lane >> 4;
    const int nbase = blockIdx.x * NB;

    const bf16x8* tW2aT = (const bf16x8*)tab + 7 * 512;
    const bf16x8* tWc   = (const bf16x8*)tab + 11 * 512;
    const bf16x8* tW2b  = (const bf16x8*)tab + 15 * 512;

    const int nodeA = min(nbase + wave * 16 + l15, N - 1);
    const int cntA  = offsets[nodeA + 1] - offsets[nodeA];
    const float invc = 1.f / fmaxf((float)cntA, 1.f);
    const int kq = quad * 8;

    f32x4 acc[8];

    // ===== GEMM1: pre = concat(x, sums/cnt) @ [W2a_top; Wc]  (K=256) =====
#pragma unroll
    for (int nt = 0; nt < 8; ++nt) acc[nt] = (f32x4){0.f, 0.f, 0.f, 0.f};
#pragma unroll
    for (int ks = 0; ks < 8; ++ks) {
        bf16x8 a;
        if (ks < 4) {
            const float* b0 = &x[(long)nodeA * DN + ks * 32 + kq];
            a = pk8(*(const float4*)b0, *(const float4*)(b0 + 4));
        } else {
            const float* sp = &sums[(long)nodeA * DO + (ks - 4) * 32 + kq];
            float4 p = *(const float4*)sp;
            float4 q = *(const float4*)(sp + 4);
            p.x *= invc; p.y *= invc; p.z *= invc; p.w *= invc;
            q.x *= invc; q.y *= invc; q.z *= invc; q.w *= invc;
            a = pk8(p, q);
        }
        const bf16x8* tB = (ks < 4) ? tW2aT : tWc;
        const int kk = (ks < 4) ? ks : ks - 4;
#pragma unroll
        for (int nt = 0; nt < 8; ++nt) {
            bf16x8 b = tB[(kk * 8 + nt) * 64 + lane];
            acc[nt] = __builtin_amdgcn_mfma_f32_16x16x32_bf16(a, b, acc[nt], 0, 0, 0);
        }
    }
    // bias (+ cnt-gated folded b1b term) + leaky + LN -> hn (bf16) LDS tile
    {
        float ba[8], gg[8], bb[8], bcv[8];
#pragma unroll
        for (int nt = 0; nt < 8; ++nt) {
            int col = nt * 16 + l15;
            ba[nt] = b2a[col]; gg[nt] = g2[col]; bb[nt] = be2[col]; bcv[nt] = bc[col];
        }
#pragma unroll
        for (int reg = 0; reg < 4; ++reg) {
            int nodeC = nbase + wave * 16 + quad * 4 + reg;
            int cc = (nodeC < N) ? (offsets[nodeC + 1] - offsets[nodeC]) : 0;
            float cf = (cc > 0) ? 1.f : 0.f;
            float v[8];
            float s = 0.f, q = 0.f;
#pragma unroll
            for (int nt = 0; nt < 8; ++nt) {
                float t = acc[nt][reg] + ba[nt] + cf * bcv[nt];
                t = (t >= 0.f) ? t : NEG_SLOPE * t;
                v[nt] = t; s += t; q += t * t;
            }
#pragma unroll
            for (int off = 1; off < 16; off <<= 1) {
                s += __shfl_xor(s, off, 64);
                q += __shfl_xor(q, off, 64);
            }
            float mu  = s * (1.f / DO);
            float var = q * (1.f / DO) - mu * mu;
            float rs  = rsqrtf(var + LN_EPS);
            int lrow = quad * 4 + reg;
#pragma unroll
            for (int nt = 0; nt < 8; ++nt) {
                float h = (v[nt] - mu) * rs * gg[nt] + bb[nt];
                s_t[wave][lrow * T_LD + nt * 16 + l15] = f2bf(h);
            }
        }
    }

    // ===== GEMM2: out = hn @ W2b + b2b  (K=128) =====
#pragma unroll
    for (int nt = 0; nt < 8; ++nt) acc[nt] = (f32x4){0.f, 0.f, 0.f, 0.f};
#pragma unroll
    for (int ks = 0; ks < 4; ++ks) {
        bf16x8 a = *(const bf16x8*)&s_t[wave][l15 * T_LD + ks * 32 + kq];
#pragma unroll
        for (int nt = 0; nt < 8; ++nt) {
            bf16x8 b = tW2b[(ks * 8 + nt) * 64 + lane];
            acc[nt] = __builtin_amdgcn_mfma_f32_16x16x32_bf16(a, b, acc[nt], 0, 0, 0);
        }
    }
    {
#pragma unroll
        for (int reg = 0; reg < 4; ++reg) {
            int nodeC = nbase + wave * 16 + quad * 4 + reg;
            if (nodeC < N) {
                long base = (long)nodeC * DO;
#pragma unroll
                for (int nt = 0; nt < 8; ++nt)
                    out[base + nt * 16 + l15] = acc[nt][reg] + b2b[nt * 16 + l15];
            }
        }
    }
}

// ---------------------------------------------------------------------------
extern "C" void kernel_launch(void* const* d_in, const int* in_sizes, int n_in,
                              void* d_out, int out_size, void* d_ws, size_t ws_size,
                              hipStream_t stream)
{
    const float* x          = (const float*)d_in[0];
    const int*   edge_index = (const int*)d_in[1];
    const float* edge_attr  = (const float*)d_in[2];
    const float* u          = (const float*)d_in[3];
    const float* W1a = (const float*)d_in[5];
    const float* b1a = (const float*)d_in[6];
    const float* g1  = (const float*)d_in[7];
    const float* be1 = (const float*)d_in[8];
    const float* W1b = (const float*)d_in[9];
    const float* b1b = (const float*)d_in[10];
    const float* W2a = (const float*)d_in[11];
    const float* b2a = (const float*)d_in[12];
    const float* g2  = (const float*)d_in[13];
    const float* be2 = (const float*)d_in[14];
    const float* W2b = (const float*)d_in[15];
    const float* b2b = (const float*)d_in[16];

    const int N = in_sizes[0] / DN;   // 50000
    const int E = in_sizes[2] / DE;   // 800000
    float* out  = (float*)d_out;

    // ws layout (all 8/16B aligned):
    //   sorted[E] int2 (6.4MB) | tab 19*512*8 bf16 (152KB) | bc[128] f32 |
    //   counts[N] | offsets[N+1] | cursor[N]           total ~7.2MB
    // sums (f32 [N][DO]) lives in d_out; node_kernel reads its own slice
    // before overwriting it with out.
    char* p = (char*)d_ws;
    int2* sorted = (int2*)p;                      p += (size_t)E * sizeof(int2);
    unsigned short* tab = (unsigned short*)p;     p += (size_t)19 * 512 * 8 * sizeof(unsigned short);
    float* bc = (float*)p;                        p += 128 * sizeof(float);
    int* counts = (int*)p;                        p += (size_t)N * sizeof(int);
    int* offsets = (int*)p;                       p += (size_t)(N + 1) * sizeof(int);
    p = (char*)(((uintptr_t)p + 15) & ~(uintptr_t)15);
    int* cursor = (int*)p;                        p += (size_t)N * sizeof(int);
    float* sums = (float*)d_out;

    (void)hipMemsetAsync(counts, 0, (size_t)N * sizeof(int), stream);
    (void)hipMemsetAsync(d_out, 0, (size_t)N * DO * sizeof(float), stream);

    wprep_kernel<<<(19 * 512 + 128 + 255) / 256, 256, 0, stream>>>(
        W1a, W1b, W2a, W2b, b1b, tab, bc);

    hist_kernel<<<(E + 255) / 256, 256, 0, stream>>>(edge_index, counts, E);
    scan_kernel<<<1, 1024, 0, stream>>>(counts, offsets, cursor, N);
    scatter_kernel<<<(E + 255) / 256, 256, 0, stream>>>(edge_index, cursor, sorted, E);

    const int eblocks = (E + EPB - 1) / EPB;
    edge_kernel<<<eblocks, 256, 0, stream>>>(
        x, edge_index, edge_attr, u, sorted, tab, b1a, g1, be1, sums, E);

    const int nblocks = (N + NB - 1) / NB;
    node_kernel<<<nblocks, 256, 0, stream>>>(
        x, sums, offsets, tab, bc, b2a, g2, be2, b2b, out, N);
}

// Round 2
// 728.651 us; speedup vs baseline: 1.1065x; 1.1065x over previous
//
#include <hip/hip_runtime.h>
#include <hip/hip_fp16.h>
#include <hip/hip_bf16.h>

// Problem constants
constexpr int DN = 128, DE = 64, DG = 32, DO = 128;
constexpr float NEG_SLOPE = 0.01f;
constexpr float LN_EPS = 1e-5f;

constexpr int EPB = 128;   // edges per block (4 waves x 32 edges)
constexpr int NB  = 64;    // nodes per block (4 waves x 16 nodes)
constexpr int T_LD = 136;  // node per-wave LDS row stride in shorts (272B)
constexpr int H_LD = 132;  // edge h-tile LDS row stride in halves (264B)

typedef __attribute__((ext_vector_type(8))) short bf16x8;
typedef __attribute__((ext_vector_type(4))) float f32x4;

__device__ inline unsigned short f2bf(float f) {
    unsigned u = __builtin_bit_cast(unsigned, f);
    u += 0x7FFFu + ((u >> 16) & 1u);
    return (unsigned short)(u >> 16);
}

__device__ inline bf16x8 pk8(float4 p, float4 q) {
    bf16x8 r;
    r[0] = (short)f2bf(p.x); r[1] = (short)f2bf(p.y);
    r[2] = (short)f2bf(p.z); r[3] = (short)f2bf(p.w);
    r[4] = (short)f2bf(q.x); r[5] = (short)f2bf(q.y);
    r[6] = (short)f2bf(q.z); r[7] = (short)f2bf(q.w);
    return r;
}

// ---------------------------------------------------------------------------
// Weight prep. Fragment-ordered bf16 tables, B-frag layout for
// mfma_f32_16x16x32_bf16: B[n = nt*16+(lane&15)][k = ks*32+(lane>>4)*8+j].
// Slab-sets (512 frag-lanes each):
//   [0,6)   W1a rows 0..191 (x | edge_attr; the u rows are folded into b1ap)
//   [6,10)  W2a rows 0..127 (x part of concat)
//   [10,14) Wc = W1b @ W2a[128:256,:]   (folded: agg GEMM eliminated)
//   [14,18) W2b
// Extra threads: bc[n] = b1b @ W2a_bot ; b1ap[n] = b1a[n] + u @ W1a[192:224,:]
// ---------------------------------------------------------------------------
__global__ void wprep_kernel(const float* __restrict__ W1a,
                             const float* __restrict__ W1b,
                             const float* __restrict__ W2a,
                             const float* __restrict__ W2b,
                             const float* __restrict__ b1a,
                             const float* __restrict__ b1b,
                             const float* __restrict__ u,
                             unsigned short* __restrict__ tab,
                             float* __restrict__ bc,
                             float* __restrict__ b1ap) {
    int idx = blockIdx.x * 256 + threadIdx.x;
    if (idx >= 18 * 512 + 256) return;
    if (idx >= 18 * 512 + 128) {           // b1ap = b1a + u @ W1a[192:224,:]
        int n = idx - (18 * 512 + 128);
        float s = b1a[n];
        for (int k = 0; k < DG; ++k) s += u[k] * W1a[(long)(192 + k) * DO + n];
        b1ap[n] = s;
        return;
    }
    if (idx >= 18 * 512) {                 // bc = b1b @ W2a_bot
        int n = idx - 18 * 512;
        float s = 0.f;
        for (int j = 0; j < DO; ++j) s += b1b[j] * W2a[(long)(DN + j) * DO + n];
        bc[n] = s;
        return;
    }
    int slabset = idx >> 9;
    int rem = idx & 511;
    int nt = rem >> 6, lane = rem & 63;
    int quad = lane >> 4, l15 = lane & 15;
    int n = nt * 16 + l15;
    union { ushort4 u4[2]; unsigned short s[8]; } o;
    if (slabset < 6) {
        int k0 = slabset * 32 + quad * 8;
#pragma unroll
        for (int j = 0; j < 8; ++j) o.s[j] = f2bf(W1a[(long)(k0 + j) * DO + n]);
    } else if (slabset < 10) {
        int k0 = (slabset - 6) * 32 + quad * 8;
#pragma unroll
        for (int j = 0; j < 8; ++j) o.s[j] = f2bf(W2a[(long)(k0 + j) * DO + n]);
    } else if (slabset < 14) {
        int k0 = (slabset - 10) * 32 + quad * 8;
        float s[8] = {0.f, 0.f, 0.f, 0.f, 0.f, 0.f, 0.f, 0.f};
        for (int j2 = 0; j2 < DO; ++j2) {
            float wa = W2a[(long)(DN + j2) * DO + n];
#pragma unroll
            for (int j = 0; j < 8; ++j) s[j] += W1b[(long)(k0 + j) * DO + j2] * wa;
        }
#pragma unroll
        for (int j = 0; j < 8; ++j) o.s[j] = f2bf(s[j]);
    } else {
        int k0 = (slabset - 14) * 32 + quad * 8;
#pragma unroll
        for (int j = 0; j < 8; ++j) o.s[j] = f2bf(W2b[(long)(k0 + j) * DO + n]);
    }
    *(ushort4*)&tab[(long)idx * 8]     = o.u4[0];
    *(ushort4*)&tab[(long)idx * 8 + 4] = o.u4[1];
}

// ---------------------------------------------------------------------------
// CSR build: histogram -> parallel 3-stage scan -> slot scatter.
// ---------------------------------------------------------------------------
__global__ void hist_kernel(const int* __restrict__ edge_index,
                            int* __restrict__ counts, int E) {
    int e = blockIdx.x * 256 + threadIdx.x;
    if (e < E) atomicAdd(&counts[edge_index[E + e]], 1);
}

// per-1024-chunk exclusive scan; chunk totals -> partials
__global__ __launch_bounds__(1024) void scan1_kernel(
    const int* __restrict__ counts, int* __restrict__ offsets,
    int* __restrict__ partials, int N) {
    __shared__ int s_ws[16];
    const int tid = threadIdx.x, lane = tid & 63, wv = tid >> 6;
    int i = blockIdx.x * 1024 + tid;
    int v = (i < N) ? counts[i] : 0;
    int s = v;
#pragma unroll
    for (int off = 1; off < 64; off <<= 1) {
        int t = __shfl_up(s, off, 64);
        if (lane >= off) s += t;
    }
    if (lane == 63) s_ws[wv] = s;
    __syncthreads();
    if (tid < 16) {
        int w = s_ws[tid];
#pragma unroll
        for (int off = 1; off < 16; off <<= 1) {
            int t = __shfl_up(w, off, 16);
            if (tid >= off) w += t;
        }
        s_ws[tid] = w;
    }
    __syncthreads();
    int wbase = wv ? s_ws[wv - 1] : 0;
    if (i < N) offsets[i] = wbase + s - v;      // chunk-local exclusive
    if (tid == 0) partials[blockIdx.x] = s_ws[15];
}

// exclusive scan of chunk totals (1 wave, loop with carry)
__global__ void scan2_kernel(int* __restrict__ partials, int P) {
    const int t = threadIdx.x;   // 64
    int carry = 0;
    for (int base = 0; base < P; base += 64) {
        int idx = base + t;
        int v = (idx < P) ? partials[idx] : 0;
        int s = v;
#pragma unroll
        for (int off = 1; off < 64; off <<= 1) {
            int w = __shfl_up(s, off, 64);
            if (t >= off) s += w;
        }
        if (idx < P) partials[idx] = carry + s - v;
        carry += __shfl(s, 63, 64);
    }
}

// add chunk base; init cursor; offsets[N] = E
__global__ __launch_bounds__(1024) void scan3_kernel(
    int* __restrict__ offsets, const int* __restrict__ partials,
    int* __restrict__ cursor, int N, int E) {
    int i = blockIdx.x * 1024 + threadIdx.x;
    if (i < N) {
        int o = offsets[i] + partials[blockIdx.x];
        offsets[i] = o; cursor[i] = o;
    }
    if (i == 0) offsets[N] = E;
}

__global__ void scatter_kernel(const int* __restrict__ edge_index,
                               int* __restrict__ cursor,
                               int2* __restrict__ sorted, int E) {
    int e = blockIdx.x * 256 + threadIdx.x;
    if (e < E) {
        int d = edge_index[E + e];
        int pos = atomicAdd(&cursor[d], 1);
        sorted[pos] = make_int2(e, d);
    }
}

// ---------------------------------------------------------------------------
// Edge kernel over DEST-SORTED edges:
//   h1 = concat(x[src], edge_attr) @ W1a[0:192] (+ u-term folded into b1ap)
//   h  = LN(leaky(h1+b1ap)) -> f16 LDS tile; run-reduction in f32;
//   NATIVE f32 atomics (unsafeAtomicAdd -> global_atomic_add_f32, no CAS loop).
// ---------------------------------------------------------------------------
__global__ __launch_bounds__(256) void edge_kernel(
    const float* __restrict__ x, const int* __restrict__ edge_index,
    const float* __restrict__ edge_attr,
    const int2* __restrict__ sorted, const unsigned short* __restrict__ tab,
    const float* __restrict__ b1ap, const float* __restrict__ g1,
    const float* __restrict__ be1,
    float* __restrict__ sums, int E)
{
    __shared__ int s_src[EPB], s_eid[EPB], s_dst[EPB];
    __shared__ alignas(16) __half s_h[EPB * H_LD];   // 33.8 KB

    const int tid = threadIdx.x, lane = tid & 63, wave = tid >> 6;
    const int l15 = lane & 15, quad = lane >> 4;
    const int ebase = blockIdx.x * EPB;
    const int evalid = min(EPB, E - ebase);

    if (tid < EPB) {
        bool v = tid < evalid;
        int2 ed = v ? sorted[ebase + tid] : make_int2(0, 0);
        s_eid[tid] = ed.x;
        s_dst[tid] = ed.y;
        s_src[tid] = edge_index[ed.x];
    }
    __syncthreads();

    const int r0 = wave * 32 + l15, r1 = r0 + 16;
    const long xs0 = (long)s_src[r0] * DN;
    const long xs1 = (long)s_src[r1] * DN;
    const long er0 = (long)s_eid[r0] * DE;
    const long er1 = (long)s_eid[r1] * DE;
    const bf16x8* tW1a = (const bf16x8*)tab;   // slab-sets 0..5
    const int kq = quad * 8;

    f32x4 acc[2][8];
#pragma unroll
    for (int mt = 0; mt < 2; ++mt)
#pragma unroll
        for (int nt = 0; nt < 8; ++nt) acc[mt][nt] = (f32x4){0.f, 0.f, 0.f, 0.f};

#pragma unroll
    for (int ks = 0; ks < 6; ++ks) {
        float4 p0, q0, p1, q1;
        if (ks < 4) {
            const float* b0 = &x[xs0 + ks * 32 + kq];
            const float* b1 = &x[xs1 + ks * 32 + kq];
            p0 = *(const float4*)b0; q0 = *(const float4*)(b0 + 4);
            p1 = *(const float4*)b1; q1 = *(const float4*)(b1 + 4);
        } else {
            int c = ks * 32 - DN + kq;
            const float* b0 = &edge_attr[er0 + c];
            const float* b1 = &edge_attr[er1 + c];
            p0 = *(const float4*)b0; q0 = *(const float4*)(b0 + 4);
            p1 = *(const float4*)b1; q1 = *(const float4*)(b1 + 4);
        }
        bf16x8 a0 = pk8(p0, q0);
        bf16x8 a1 = pk8(p1, q1);
#pragma unroll
        for (int nt = 0; nt < 8; ++nt) {
            bf16x8 b = tW1a[(ks * 8 + nt) * 64 + lane];
            acc[0][nt] = __builtin_amdgcn_mfma_f32_16x16x32_bf16(a0, b, acc[0][nt], 0, 0, 0);
            acc[1][nt] = __builtin_amdgcn_mfma_f32_16x16x32_bf16(a1, b, acc[1][nt], 0, 0, 0);
        }
    }

    // bias + LeakyReLU + LayerNorm -> f16 LDS tile
    float ba[8], gg[8], bb[8];
#pragma unroll
    for (int nt = 0; nt < 8; ++nt) {
        int col = nt * 16 + l15;
        ba[nt] = b1ap[col]; gg[nt] = g1[col]; bb[nt] = be1[col];
    }
#pragma unroll
    for (int mt = 0; mt < 2; ++mt) {
#pragma unroll
        for (int r = 0; r < 4; ++r) {
            float v[8];
            float s = 0.f, q = 0.f;
#pragma unroll
            for (int nt = 0; nt < 8; ++nt) {
                float t = acc[mt][nt][r] + ba[nt];
                t = (t >= 0.f) ? t : NEG_SLOPE * t;
                v[nt] = t; s += t; q += t * t;
            }
#pragma unroll
            for (int off = 1; off < 16; off <<= 1) {
                s += __shfl_xor(s, off, 64);
                q += __shfl_xor(q, off, 64);
            }
            float mu  = s * (1.f / DO);
            float var = q * (1.f / DO) - mu * mu;
            float rs  = rsqrtf(var + LN_EPS);
            int lrow = wave * 32 + mt * 16 + quad * 4 + r;
#pragma unroll
            for (int nt = 0; nt < 8; ++nt) {
                float h  = (v[nt] - mu) * rs * gg[nt] + bb[nt];
                float hp = __shfl_xor(h, 1, 64);
                if ((l15 & 1) == 0) {
                    *(__half2*)&s_h[lrow * H_LD + nt * 16 + l15] =
                        __halves2half2(__float2half_rn(h), __float2half_rn(hp));
                }
            }
        }
    }
    __syncthreads();

    // run-reduction: 4 waves x 32 edges; lane owns dim-pair (2*lane, 2*lane+1);
    // flush one native f32 atomic pair per dest-run.
    {
        const int d2 = lane * 2;
        int e0 = wave * 32, e1 = min(e0 + 32, evalid);
        if (e0 < e1) {
            float a0 = 0.f, a1 = 0.f;
            int cur = s_dst[e0];
            if (e1 - e0 == 32) {
#pragma unroll
                for (int k = 0; k < 32; ++k) {
                    int e = e0 + k;
                    int dd = s_dst[e];          // wave-uniform
                    if (dd != cur) {
                        unsafeAtomicAdd(&sums[(long)cur * DO + d2], a0);
                        unsafeAtomicAdd(&sums[(long)cur * DO + d2 + 1], a1);
                        a0 = a1 = 0.f; cur = dd;
                    }
                    float2 hv = __half22float2(*(const __half2*)&s_h[e * H_LD + d2]);
                    a0 += hv.x; a1 += hv.y;
                }
            } else {
                for (int e = e0; e < e1; ++e) {
                    int dd = s_dst[e];
                    if (dd != cur) {
                        unsafeAtomicAdd(&sums[(long)cur * DO + d2], a0);
                        unsafeAtomicAdd(&sums[(long)cur * DO + d2 + 1], a1);
                        a0 = a1 = 0.f; cur = dd;
                    }
                    float2 hv = __half22float2(*(const __half2*)&s_h[e * H_LD + d2]);
                    a0 += hv.x; a1 += hv.y;
                }
            }
            unsafeAtomicAdd(&sums[(long)cur * DO + d2], a0);
            unsafeAtomicAdd(&sums[(long)cur * DO + d2 + 1], a1);
        }
    }
}

// ---------------------------------------------------------------------------
// Node kernel (GEMM0 folded away via Wc = W1b@W2a_bot):
//   pre = x @ W2a_top + (sums/max(cnt,1)) @ Wc + b2a + (cnt>0)*bc
//   out = LN(leaky(pre)) @ W2b + b2b
// cnt from CSR offsets. sums lives in d_out (f32); each block reads only its
// own node slice before overwriting it with out.
// ---------------------------------------------------------------------------
__global__ __launch_bounds__(256) void node_kernel(
    const float* __restrict__ x, const float* __restrict__ sums,
    const int* __restrict__ offsets, const unsigned short* __restrict__ tab,
    const float* __restrict__ bc,
    const float* __restrict__ b2a, const float* __restrict__ g2,
    const float* __restrict__ be2, const float* __restrict__ b2b,
    float* __restrict__ out, int N)
{
    __shared__ unsigned short s_t[4][16 * T_LD];  // per-wave [16 rows][128 cols]

    const int tid = threadIdx.x, lane = tid & 63, wave = tid >> 6;
    const int l15 = lane & 15, quad = lane >> 4;
    const int nbase = blockIdx.x * NB;

    const bf16x8* tW2aT = (const bf16x8*)tab + 6 * 512;
    const bf16x8* tWc   = (const bf16x8*)tab + 10 * 512;
    const bf16x8* tW2b  = (const bf16x8*)tab + 14 * 512;

    const int nodeA = min(nbase + wave * 16 + l15, N - 1);
    const int cntA  = offsets[nodeA + 1] - offsets[nodeA];
    const float invc = 1.f / fmaxf((float)cntA, 1.f);
    const int kq = quad * 8;

    f32x4 acc[8];

    // ===== GEMM1: pre = concat(x, sums/cnt) @ [W2a_top; Wc]  (K=256) =====
#pragma unroll
    for (int nt = 0; nt < 8; ++nt) acc[nt] = (f32x4){0.f, 0.f, 0.f, 0.f};
#pragma unroll
    for (int ks = 0; ks < 8; ++ks) {
        bf16x8 a;
        if (ks < 4) {
            const float* b0 = &x[(long)nodeA * DN + ks * 32 + kq];
            a = pk8(*(const float4*)b0, *(const float4*)(b0 + 4));
        } else {
            const float* sp = &sums[(long)nodeA * DO + (ks - 4) * 32 + kq];
            float4 p = *(const float4*)sp;
            float4 q = *(const float4*)(sp + 4);
            p.x *= invc; p.y *= invc; p.z *= invc; p.w *= invc;
            q.x *= invc; q.y *= invc; q.z *= invc; q.w *= invc;
            a = pk8(p, q);
        }
        const bf16x8* tB = (ks < 4) ? tW2aT : tWc;
        const int kk = (ks < 4) ? ks : ks - 4;
#pragma unroll
        for (int nt = 0; nt < 8; ++nt) {
            bf16x8 b = tB[(kk * 8 + nt) * 64 + lane];
            acc[nt] = __builtin_amdgcn_mfma_f32_16x16x32_bf16(a, b, acc[nt], 0, 0, 0);
        }
    }
    // bias (+ cnt-gated folded b1b term) + leaky + LN -> hn (bf16) LDS tile
    {
        float ba[8], gg[8], bb[8], bcv[8];
#pragma unroll
        for (int nt = 0; nt < 8; ++nt) {
            int col = nt * 16 + l15;
            ba[nt] = b2a[col]; gg[nt] = g2[col]; bb[nt] = be2[col]; bcv[nt] = bc[col];
        }
#pragma unroll
        for (int reg = 0; reg < 4; ++reg) {
            int nodeC = nbase + wave * 16 + quad * 4 + reg;
            int cc = (nodeC < N) ? (offsets[nodeC + 1] - offsets[nodeC]) : 0;
            float cf = (cc > 0) ? 1.f : 0.f;
            float v[8];
            float s = 0.f, q = 0.f;
#pragma unroll
            for (int nt = 0; nt < 8; ++nt) {
                float t = acc[nt][reg] + ba[nt] + cf * bcv[nt];
                t = (t >= 0.f) ? t : NEG_SLOPE * t;
                v[nt] = t; s += t; q += t * t;
            }
#pragma unroll
            for (int off = 1; off < 16; off <<= 1) {
                s += __shfl_xor(s, off, 64);
                q += __shfl_xor(q, off, 64);
            }
            float mu  = s * (1.f / DO);
            float var = q * (1.f / DO) - mu * mu;
            float rs  = rsqrtf(var + LN_EPS);
            int lrow = quad * 4 + reg;
#pragma unroll
            for (int nt = 0; nt < 8; ++nt) {
                float h = (v[nt] - mu) * rs * gg[nt] + bb[nt];
                s_t[wave][lrow * T_LD + nt * 16 + l15] = f2bf(h);
            }
        }
    }

    // ===== GEMM2: out = hn @ W2b + b2b  (K=128) =====
#pragma unroll
    for (int nt = 0; nt < 8; ++nt) acc[nt] = (f32x4){0.f, 0.f, 0.f, 0.f};
#pragma unroll
    for (int ks = 0; ks < 4; ++ks) {
        bf16x8 a = *(const bf16x8*)&s_t[wave][l15 * T_LD + ks * 32 + kq];
#pragma unroll
        for (int nt = 0; nt < 8; ++nt) {
            bf16x8 b = tW2b[(ks * 8 + nt) * 64 + lane];
            acc[nt] = __builtin_amdgcn_mfma_f32_16x16x32_bf16(a, b, acc[nt], 0, 0, 0);
        }
    }
    {
#pragma unroll
        for (int reg = 0; reg < 4; ++reg) {
            int nodeC = nbase + wave * 16 + quad * 4 + reg;
            if (nodeC < N) {
                long base = (long)nodeC * DO;
#pragma unroll
                for (int nt = 0; nt < 8; ++nt)
                    out[base + nt * 16 + l15] = acc[nt][reg] + b2b[nt * 16 + l15];
            }
        }
    }
}

// ---------------------------------------------------------------------------
extern "C" void kernel_launch(void* const* d_in, const int* in_sizes, int n_in,
                              void* d_out, int out_size, void* d_ws, size_t ws_size,
                              hipStream_t stream)
{
    const float* x          = (const float*)d_in[0];
    const int*   edge_index = (const int*)d_in[1];
    const float* edge_attr  = (const float*)d_in[2];
    const float* u          = (const float*)d_in[3];
    const float* W1a = (const float*)d_in[5];
    const float* b1a = (const float*)d_in[6];
    const float* g1  = (const float*)d_in[7];
    const float* be1 = (const float*)d_in[8];
    const float* W1b = (const float*)d_in[9];
    const float* b1b = (const float*)d_in[10];
    const float* W2a = (const float*)d_in[11];
    const float* b2a = (const float*)d_in[12];
    const float* g2  = (const float*)d_in[13];
    const float* be2 = (const float*)d_in[14];
    const float* W2b = (const float*)d_in[15];
    const float* b2b = (const float*)d_in[16];

    const int N = in_sizes[0] / DN;   // 50000
    const int E = in_sizes[2] / DE;   // 800000
    float* out  = (float*)d_out;

    // ws layout (16B-aligned chunks):
    //   sorted[E] int2 | tab 18*512*8 bf16 | bc[128] | b1ap[128] |
    //   counts[N] | offsets[N+1] | partials[64] | cursor[N]    (~7.2MB)
    // sums (f32 [N][DO]) lives in d_out; node_kernel reads only its own
    // node slice before overwriting it with out.
    char* p = (char*)d_ws;
    int2* sorted = (int2*)p;                   p += (size_t)E * sizeof(int2);
    unsigned short* tab = (unsigned short*)p;  p += (size_t)18 * 512 * 8 * sizeof(unsigned short);
    float* bc = (float*)p;                     p += 128 * sizeof(float);
    float* b1ap = (float*)p;                   p += 128 * sizeof(float);
    int* counts = (int*)p;                     p += (size_t)N * sizeof(int);
    int* offsets = (int*)p;                    p += (size_t)(N + 1) * sizeof(int);
    p = (char*)(((uintptr_t)p + 15) & ~(uintptr_t)15);
    int* partials = (int*)p;                   p += 64 * sizeof(int);
    int* cursor = (int*)p;                     p += (size_t)N * sizeof(int);
    float* sums = (float*)d_out;

    (void)hipMemsetAsync(counts, 0, (size_t)N * sizeof(int), stream);
    (void)hipMemsetAsync(d_out, 0, (size_t)N * DO * sizeof(float), stream);

    wprep_kernel<<<(18 * 512 + 256 + 255) / 256, 256, 0, stream>>>(
        W1a, W1b, W2a, W2b, b1a, b1b, u, tab, bc, b1ap);

    const int P = (N + 1023) / 1024;   // 49 chunks
    hist_kernel<<<(E + 255) / 256, 256, 0, stream>>>(edge_index, counts, E);
    scan1_kernel<<<P, 1024, 0, stream>>>(counts, offsets, partials, N);
    scan2_kernel<<<1, 64, 0, stream>>>(partials, P);
    scan3_kernel<<<P, 1024, 0, stream>>>(offsets, partials, cursor, N, E);
    scatter_kernel<<<(E + 255) / 256, 256, 0, stream>>>(edge_index, cursor, sorted, E);

    const int eblocks = (E + EPB - 1) / EPB;
    edge_kernel<<<eblocks, 256, 0, stream>>>(
        x, edge_index, edge_attr, sorted, tab, b1ap, g1, be1, sums, E);

    const int nblocks = (N + NB - 1) / NB;
    node_kernel<<<nblocks, 256, 0, stream>>>(
        x, sums, offsets, tab, bc, b2a, g2, be2, b2b, out, N);
}

// Round 3
// 690.650 us; speedup vs baseline: 1.1674x; 1.0550x over previous
//
#include <hip/hip_runtime.h>
#include <hip/hip_fp16.h>
#include <hip/hip_bf16.h>

// Problem constants
constexpr int DN = 128, DE = 64, DG = 32, DO = 128;
constexpr float NEG_SLOPE = 0.01f;
constexpr float LN_EPS = 1e-5f;

constexpr int EPB = 128;   // edges per block (4 waves x 32 edges, waves independent)
constexpr int NB  = 16;    // nodes per block (1 wave x 16 nodes)
constexpr int T_LD = 136;  // node LDS row stride in shorts (272B)
constexpr int H_LD = 132;  // edge h-tile LDS row stride in halves (264B)

typedef __attribute__((ext_vector_type(8))) short bf16x8;
typedef __attribute__((ext_vector_type(4))) float f32x4;

__device__ inline unsigned short f2bf(float f) {
    unsigned u = __builtin_bit_cast(unsigned, f);
    u += 0x7FFFu + ((u >> 16) & 1u);
    return (unsigned short)(u >> 16);
}

__device__ inline bf16x8 pk8(float4 p, float4 q) {
    bf16x8 r;
    r[0] = (short)f2bf(p.x); r[1] = (short)f2bf(p.y);
    r[2] = (short)f2bf(p.z); r[3] = (short)f2bf(p.w);
    r[4] = (short)f2bf(q.x); r[5] = (short)f2bf(q.y);
    r[6] = (short)f2bf(q.z); r[7] = (short)f2bf(q.w);
    return r;
}

// ---------------------------------------------------------------------------
// Weight prep. Fragment-ordered bf16 tables, B-frag layout for
// mfma_f32_16x16x32_bf16: B[n = nt*16+(lane&15)][k = ks*32+(lane>>4)*8+j].
// Slab-sets: [0,6) W1a[0:192]; [6,10) W2a[0:128]; [10,14) Wc=W1b@W2a_bot;
// [14,18) W2b. Extra: bc = b1b@W2a_bot ; b1ap = b1a + u@W1a[192:224].
// ---------------------------------------------------------------------------
__global__ void wprep_kernel(const float* __restrict__ W1a,
                             const float* __restrict__ W1b,
                             const float* __restrict__ W2a,
                             const float* __restrict__ W2b,
                             const float* __restrict__ b1a,
                             const float* __restrict__ b1b,
                             const float* __restrict__ u,
                             unsigned short* __restrict__ tab,
                             float* __restrict__ bc,
                             float* __restrict__ b1ap) {
    int idx = blockIdx.x * 256 + threadIdx.x;
    if (idx >= 18 * 512 + 256) return;
    if (idx >= 18 * 512 + 128) {           // b1ap = b1a + u @ W1a[192:224,:]
        int n = idx - (18 * 512 + 128);
        float s = b1a[n];
        for (int k = 0; k < DG; ++k) s += u[k] * W1a[(long)(192 + k) * DO + n];
        b1ap[n] = s;
        return;
    }
    if (idx >= 18 * 512) {                 // bc = b1b @ W2a_bot
        int n = idx - 18 * 512;
        float s = 0.f;
        for (int j = 0; j < DO; ++j) s += b1b[j] * W2a[(long)(DN + j) * DO + n];
        bc[n] = s;
        return;
    }
    int slabset = idx >> 9;
    int rem = idx & 511;
    int nt = rem >> 6, lane = rem & 63;
    int quad = lane >> 4, l15 = lane & 15;
    int n = nt * 16 + l15;
    union { ushort4 u4[2]; unsigned short s[8]; } o;
    if (slabset < 6) {
        int k0 = slabset * 32 + quad * 8;
#pragma unroll
        for (int j = 0; j < 8; ++j) o.s[j] = f2bf(W1a[(long)(k0 + j) * DO + n]);
    } else if (slabset < 10) {
        int k0 = (slabset - 6) * 32 + quad * 8;
#pragma unroll
        for (int j = 0; j < 8; ++j) o.s[j] = f2bf(W2a[(long)(k0 + j) * DO + n]);
    } else if (slabset < 14) {
        int k0 = (slabset - 10) * 32 + quad * 8;
        float s[8] = {0.f, 0.f, 0.f, 0.f, 0.f, 0.f, 0.f, 0.f};
        for (int j2 = 0; j2 < DO; ++j2) {
            float wa = W2a[(long)(DN + j2) * DO + n];
#pragma unroll
            for (int j = 0; j < 8; ++j) s[j] += W1b[(long)(k0 + j) * DO + j2] * wa;
        }
#pragma unroll
        for (int j = 0; j < 8; ++j) o.s[j] = f2bf(s[j]);
    } else {
        int k0 = (slabset - 14) * 32 + quad * 8;
#pragma unroll
        for (int j = 0; j < 8; ++j) o.s[j] = f2bf(W2b[(long)(k0 + j) * DO + n]);
    }
    *(ushort4*)&tab[(long)idx * 8]     = o.u4[0];
    *(ushort4*)&tab[(long)idx * 8 + 4] = o.u4[1];
}

// x -> bf16 once (edge gathers halve; A-frags load with zero conversion)
__global__ void xprep_kernel(const float* __restrict__ x,
                             unsigned short* __restrict__ xb, int total8) {
    int i = blockIdx.x * 256 + threadIdx.x;
    if (i < total8) {
        const float4* p = (const float4*)x + (long)i * 2;
        bf16x8 r = pk8(p[0], p[1]);
        *(bf16x8*)&xb[(long)i * 8] = r;
    }
}

// ---------------------------------------------------------------------------
// CSR build: histogram -> scan1 (per-chunk) -> scan3 (fused partial-scan +
// base-add + cursor init) -> slot scatter.
// ---------------------------------------------------------------------------
__global__ void hist_kernel(const int* __restrict__ edge_index,
                            int* __restrict__ counts, int E) {
    int e = blockIdx.x * 256 + threadIdx.x;
    if (e < E) atomicAdd(&counts[edge_index[E + e]], 1);
}

__global__ __launch_bounds__(1024) void scan1_kernel(
    const int* __restrict__ counts, int* __restrict__ offsets,
    int* __restrict__ partials, int N) {
    __shared__ int s_ws[16];
    const int tid = threadIdx.x, lane = tid & 63, wv = tid >> 6;
    int i = blockIdx.x * 1024 + tid;
    int v = (i < N) ? counts[i] : 0;
    int s = v;
#pragma unroll
    for (int off = 1; off < 64; off <<= 1) {
        int t = __shfl_up(s, off, 64);
        if (lane >= off) s += t;
    }
    if (lane == 63) s_ws[wv] = s;
    __syncthreads();
    if (tid < 16) {
        int w = s_ws[tid];
#pragma unroll
        for (int off = 1; off < 16; off <<= 1) {
            int t = __shfl_up(w, off, 16);
            if (tid >= off) w += t;
        }
        s_ws[tid] = w;
    }
    __syncthreads();
    int wbase = wv ? s_ws[wv - 1] : 0;
    if (i < N) offsets[i] = wbase + s - v;      // chunk-local exclusive
    if (tid == 0) partials[blockIdx.x] = s_ws[15];
}

// fused: wave 0 re-scans partials (P <= 64 here: N <= 65536), then all
// threads add the chunk base. Also inits cursor and offsets[N].
__global__ __launch_bounds__(1024) void scan3_kernel(
    int* __restrict__ offsets, const int* __restrict__ partials,
    int* __restrict__ cursor, int N, int E, int P) {
    __shared__ int s_base;
    const int tid = threadIdx.x;
    if (tid < 64) {
        int v = (tid < P) ? partials[tid] : 0;
        int s = v;
#pragma unroll
        for (int off = 1; off < 64; off <<= 1) {
            int t = __shfl_up(s, off, 64);
            if (tid >= off) s += t;
        }
        if (tid == (int)blockIdx.x) s_base = s - v;   // exclusive base
    }
    __syncthreads();
    int i = blockIdx.x * 1024 + tid;
    if (i < N) {
        int o = offsets[i] + s_base;
        offsets[i] = o; cursor[i] = o;
    }
    if (i == 0) offsets[N] = E;
}

__global__ void scatter_kernel(const int* __restrict__ edge_index,
                               int* __restrict__ cursor,
                               int2* __restrict__ sorted, int E) {
    int e = blockIdx.x * 256 + threadIdx.x;
    if (e < E) {
        int d = edge_index[E + e];
        int pos = atomicAdd(&cursor[d], 1);
        sorted[pos] = make_int2(e, d);
    }
}

// ---------------------------------------------------------------------------
// Edge kernel over DEST-SORTED edges — ZERO BARRIERS (all LDS is wave-
// private: each wave loads, computes, and reduces its own 32 edges).
//   h1 = concat(xb[src], edge_attr) @ W1a[0:192] (+ u-term in b1ap)
//   h  = LN(leaky(h1+b1ap)) -> f16 LDS rows; wave-local run-reduction;
//   ~3 native f32 atomic-pair flushes per wave.
// ---------------------------------------------------------------------------
__global__ __launch_bounds__(256) void edge_kernel(
    const unsigned short* __restrict__ xb, const int* __restrict__ edge_index,
    const float* __restrict__ edge_attr,
    const int2* __restrict__ sorted, const unsigned short* __restrict__ tab,
    const float* __restrict__ b1ap, const float* __restrict__ g1,
    const float* __restrict__ be1,
    float* __restrict__ sums, int E)
{
    __shared__ int s_src[EPB], s_eid[EPB], s_dst[EPB];
    __shared__ alignas(16) __half s_h[EPB * H_LD];   // 33.8 KB

    const int tid = threadIdx.x, lane = tid & 63, wave = tid >> 6;
    const int l15 = lane & 15, quad = lane >> 4;
    const int ebase = blockIdx.x * EPB;
    const int evalid = min(EPB, E - ebase);

    // wave-private descriptor load: wave reads ONLY [wave*32, wave*32+32)
    if (lane < 32) {
        int r = wave * 32 + lane;
        bool v = r < evalid;
        int2 ed = v ? sorted[ebase + r] : make_int2(0, 0);
        s_eid[r] = ed.x;
        s_dst[r] = ed.y;
        s_src[r] = edge_index[ed.x];
    }
    // no __syncthreads(): intra-wave LDS dependency only (compiler waits)

    const int r0 = wave * 32 + l15, r1 = r0 + 16;
    const long xs0 = (long)s_src[r0] * DN;
    const long xs1 = (long)s_src[r1] * DN;
    const long er0 = (long)s_eid[r0] * DE;
    const long er1 = (long)s_eid[r1] * DE;
    const bf16x8* tW1a = (const bf16x8*)tab;   // slab-sets 0..5
    const int kq = quad * 8;

    f32x4 acc[2][8];
#pragma unroll
    for (int mt = 0; mt < 2; ++mt)
#pragma unroll
        for (int nt = 0; nt < 8; ++nt) acc[mt][nt] = (f32x4){0.f, 0.f, 0.f, 0.f};

#pragma unroll
    for (int ks = 0; ks < 6; ++ks) {
        bf16x8 a0, a1;
        if (ks < 4) {
            a0 = *(const bf16x8*)&xb[xs0 + ks * 32 + kq];
            a1 = *(const bf16x8*)&xb[xs1 + ks * 32 + kq];
        } else {
            int c = ks * 32 - DN + kq;
            const float* b0 = &edge_attr[er0 + c];
            const float* b1 = &edge_attr[er1 + c];
            a0 = pk8(*(const float4*)b0, *(const float4*)(b0 + 4));
            a1 = pk8(*(const float4*)b1, *(const float4*)(b1 + 4));
        }
#pragma unroll
        for (int nt = 0; nt < 8; ++nt) {
            bf16x8 b = tW1a[(ks * 8 + nt) * 64 + lane];
            acc[0][nt] = __builtin_amdgcn_mfma_f32_16x16x32_bf16(a0, b, acc[0][nt], 0, 0, 0);
            acc[1][nt] = __builtin_amdgcn_mfma_f32_16x16x32_bf16(a1, b, acc[1][nt], 0, 0, 0);
        }
    }

    // bias + LeakyReLU + LayerNorm -> f16 LDS rows (wave-private range)
    float ba[8], gg[8], bb[8];
#pragma unroll
    for (int nt = 0; nt < 8; ++nt) {
        int col = nt * 16 + l15;
        ba[nt] = b1ap[col]; gg[nt] = g1[col]; bb[nt] = be1[col];
    }
#pragma unroll
    for (int mt = 0; mt < 2; ++mt) {
#pragma unroll
        for (int r = 0; r < 4; ++r) {
            float v[8];
            float s = 0.f, q = 0.f;
#pragma unroll
            for (int nt = 0; nt < 8; ++nt) {
                float t = acc[mt][nt][r] + ba[nt];
                t = (t >= 0.f) ? t : NEG_SLOPE * t;
                v[nt] = t; s += t; q += t * t;
            }
#pragma unroll
            for (int off = 1; off < 16; off <<= 1) {
                s += __shfl_xor(s, off, 64);
                q += __shfl_xor(q, off, 64);
            }
            float mu  = s * (1.f / DO);
            float var = q * (1.f / DO) - mu * mu;
            float rs  = rsqrtf(var + LN_EPS);
            int lrow = wave * 32 + mt * 16 + quad * 4 + r;
#pragma unroll
            for (int nt = 0; nt < 8; ++nt) {
                float h  = (v[nt] - mu) * rs * gg[nt] + bb[nt];
                float hp = __shfl_xor(h, 1, 64);
                if ((l15 & 1) == 0) {
                    *(__half2*)&s_h[lrow * H_LD + nt * 16 + l15] =
                        __halves2half2(__float2half_rn(h), __float2half_rn(hp));
                }
            }
        }
    }
    // no __syncthreads(): walk reads only this wave's rows

    // run-reduction: lane owns dim-pair (2*lane, 2*lane+1) over the wave's
    // 32 sorted edges; one native f32 atomic pair per dest-run.
    {
        const int d2 = lane * 2;
        int e0 = wave * 32, e1 = min(e0 + 32, evalid);
        if (e0 < e1) {
            float a0 = 0.f, a1 = 0.f;
            int cur = s_dst[e0];
            if (e1 - e0 == 32) {
#pragma unroll
                for (int k = 0; k < 32; ++k) {
                    int e = e0 + k;
                    int dd = s_dst[e];          // wave-uniform
                    if (dd != cur) {
                        unsafeAtomicAdd(&sums[(long)cur * DO + d2], a0);
                        unsafeAtomicAdd(&sums[(long)cur * DO + d2 + 1], a1);
                        a0 = a1 = 0.f; cur = dd;
                    }
                    float2 hv = __half22float2(*(const __half2*)&s_h[e * H_LD + d2]);
                    a0 += hv.x; a1 += hv.y;
                }
            } else {
                for (int e = e0; e < e1; ++e) {
                    int dd = s_dst[e];
                    if (dd != cur) {
                        unsafeAtomicAdd(&sums[(long)cur * DO + d2], a0);
                        unsafeAtomicAdd(&sums[(long)cur * DO + d2 + 1], a1);
                        a0 = a1 = 0.f; cur = dd;
                    }
                    float2 hv = __half22float2(*(const __half2*)&s_h[e * H_LD + d2]);
                    a0 += hv.x; a1 += hv.y;
                }
            }
            unsafeAtomicAdd(&sums[(long)cur * DO + d2], a0);
            unsafeAtomicAdd(&sums[(long)cur * DO + d2 + 1], a1);
        }
    }
}

// ---------------------------------------------------------------------------
// Node kernel — 1 wave / 16 nodes / block (3125 blocks: no tail imbalance,
// no barriers, wave-private LDS tile).
//   pre = xb @ W2a_top + (sums/max(cnt,1)) @ Wc + b2a + (cnt>0)*bc
//   out = LN(leaky(pre)) @ W2b + b2b
// ---------------------------------------------------------------------------
__global__ __launch_bounds__(64) void node_kernel(
    const unsigned short* __restrict__ xb, const float* __restrict__ sums,
    const int* __restrict__ offsets, const unsigned short* __restrict__ tab,
    const float* __restrict__ bc,
    const float* __restrict__ b2a, const float* __restrict__ g2,
    const float* __restrict__ be2, const float* __restrict__ b2b,
    float* __restrict__ out, int N)
{
    __shared__ unsigned short s_t[16 * T_LD];  // 4.4 KB

    const int lane = threadIdx.x;
    const int l15 = lane & 15, quad = lane >> 4;
    const int nbase = blockIdx.x * NB;

    const bf16x8* tW2aT = (const bf16x8*)tab + 6 * 512;
    const bf16x8* tWc   = (const bf16x8*)tab + 10 * 512;
    const bf16x8* tW2b  = (const bf16x8*)tab + 14 * 512;

    const int nodeA = min(nbase + l15, N - 1);
    const int cntA  = offsets[nodeA + 1] - offsets[nodeA];
    const float invc = 1.f / fmaxf((float)cntA, 1.f);
    const int kq = quad * 8;

    f32x4 acc[8];

    // ===== GEMM1: pre = concat(xb, sums/cnt) @ [W2a_top; Wc]  (K=256) =====
#pragma unroll
    for (int nt = 0; nt < 8; ++nt) acc[nt] = (f32x4){0.f, 0.f, 0.f, 0.f};
#pragma unroll
    for (int ks = 0; ks < 8; ++ks) {
        bf16x8 a;
        if (ks < 4) {
            a = *(const bf16x8*)&xb[(long)nodeA * DN + ks * 32 + kq];
        } else {
            const float* sp = &sums[(long)nodeA * DO + (ks - 4) * 32 + kq];
            float4 p = *(const float4*)sp;
            float4 q = *(const float4*)(sp + 4);
            p.x *= invc; p.y *= invc; p.z *= invc; p.w *= invc;
            q.x *= invc; q.y *= invc; q.z *= invc; q.w *= invc;
            a = pk8(p, q);
        }
        const bf16x8* tB = (ks < 4) ? tW2aT : tWc;
        const int kk = (ks < 4) ? ks : ks - 4;
#pragma unroll
        for (int nt = 0; nt < 8; ++nt) {
            bf16x8 b = tB[(kk * 8 + nt) * 64 + lane];
            acc[nt] = __builtin_amdgcn_mfma_f32_16x16x32_bf16(a, b, acc[nt], 0, 0, 0);
        }
    }
    // bias (+ cnt-gated folded b1b term) + leaky + LN -> hn (bf16) LDS tile
    {
        float ba[8], gg[8], bb[8], bcv[8];
#pragma unroll
        for (int nt = 0; nt < 8; ++nt) {
            int col = nt * 16 + l15;
            ba[nt] = b2a[col]; gg[nt] = g2[col]; bb[nt] = be2[col]; bcv[nt] = bc[col];
        }
#pragma unroll
        for (int reg = 0; reg < 4; ++reg) {
            int nodeC = nbase + quad * 4 + reg;
            int cc = (nodeC < N) ? (offsets[nodeC + 1] - offsets[nodeC]) : 0;
            float cf = (cc > 0) ? 1.f : 0.f;
            float v[8];
            float s = 0.f, q = 0.f;
#pragma unroll
            for (int nt = 0; nt < 8; ++nt) {
                float t = acc[nt][reg] + ba[nt] + cf * bcv[nt];
                t = (t >= 0.f) ? t : NEG_SLOPE * t;
                v[nt] = t; s += t; q += t * t;
            }
#pragma unroll
            for (int off = 1; off < 16; off <<= 1) {
                s += __shfl_xor(s, off, 64);
                q += __shfl_xor(q, off, 64);
            }
            float mu  = s * (1.f / DO);
            float var = q * (1.f / DO) - mu * mu;
            float rs  = rsqrtf(var + LN_EPS);
            int lrow = quad * 4 + reg;
#pragma unroll
            for (int nt = 0; nt < 8; ++nt) {
                float h = (v[nt] - mu) * rs * gg[nt] + bb[nt];
                s_t[lrow * T_LD + nt * 16 + l15] = f2bf(h);
            }
        }
    }

    // ===== GEMM2: out = hn @ W2b + b2b  (K=128) =====
#pragma unroll
    for (int nt = 0; nt < 8; ++nt) acc[nt] = (f32x4){0.f, 0.f, 0.f, 0.f};
#pragma unroll
    for (int ks = 0; ks < 4; ++ks) {
        bf16x8 a = *(const bf16x8*)&s_t[l15 * T_LD + ks * 32 + kq];
#pragma unroll
        for (int nt = 0; nt < 8; ++nt) {
            bf16x8 b = tW2b[(ks * 8 + nt) * 64 + lane];
            acc[nt] = __builtin_amdgcn_mfma_f32_16x16x32_bf16(a, b, acc[nt], 0, 0, 0);
        }
    }
    {
#pragma unroll
        for (int reg = 0; reg < 4; ++reg) {
            int nodeC = nbase + quad * 4 + reg;
            if (nodeC < N) {
                long base = (long)nodeC * DO;
#pragma unroll
                for (int nt = 0; nt < 8; ++nt)
                    out[base + nt * 16 + l15] = acc[nt][reg] + b2b[nt * 16 + l15];
            }
        }
    }
}

// ---------------------------------------------------------------------------
extern "C" void kernel_launch(void* const* d_in, const int* in_sizes, int n_in,
                              void* d_out, int out_size, void* d_ws, size_t ws_size,
                              hipStream_t stream)
{
    const float* x          = (const float*)d_in[0];
    const int*   edge_index = (const int*)d_in[1];
    const float* edge_attr  = (const float*)d_in[2];
    const float* u          = (const float*)d_in[3];
    const float* W1a = (const float*)d_in[5];
    const float* b1a = (const float*)d_in[6];
    const float* g1  = (const float*)d_in[7];
    const float* be1 = (const float*)d_in[8];
    const float* W1b = (const float*)d_in[9];
    const float* b1b = (const float*)d_in[10];
    const float* W2a = (const float*)d_in[11];
    const float* b2a = (const float*)d_in[12];
    const float* g2  = (const float*)d_in[13];
    const float* be2 = (const float*)d_in[14];
    const float* W2b = (const float*)d_in[15];
    const float* b2b = (const float*)d_in[16];

    const int N = in_sizes[0] / DN;   // 50000
    const int E = in_sizes[2] / DE;   // 800000
    float* out  = (float*)d_out;

    // ws layout (16B-aligned chunks), ~20 MB <= proven 25.8 MB:
    //   sorted[E] int2 (6.4M) | xb[N*DN] bf16 (12.8M) | tab (147K) |
    //   bc[128] | b1ap[128] | counts[N] | offsets[N+1] | partials[64] | cursor[N]
    // sums (f32 [N][DO]) lives in d_out; node_kernel reads only its own
    // node slice before overwriting it with out.
    char* p = (char*)d_ws;
    int2* sorted = (int2*)p;                   p += (size_t)E * sizeof(int2);
    unsigned short* xb = (unsigned short*)p;   p += (size_t)N * DN * sizeof(unsigned short);
    unsigned short* tab = (unsigned short*)p;  p += (size_t)18 * 512 * 8 * sizeof(unsigned short);
    float* bc = (float*)p;                     p += 128 * sizeof(float);
    float* b1ap = (float*)p;                   p += 128 * sizeof(float);
    int* counts = (int*)p;                     p += (size_t)N * sizeof(int);
    int* offsets = (int*)p;                    p += (size_t)(N + 1) * sizeof(int);
    p = (char*)(((uintptr_t)p + 15) & ~(uintptr_t)15);
    int* partials = (int*)p;                   p += 64 * sizeof(int);
    int* cursor = (int*)p;                     p += (size_t)N * sizeof(int);
    float* sums = (float*)d_out;

    (void)hipMemsetAsync(counts, 0, (size_t)N * sizeof(int), stream);
    (void)hipMemsetAsync(d_out, 0, (size_t)N * DO * sizeof(float), stream);

    wprep_kernel<<<(18 * 512 + 256 + 255) / 256, 256, 0, stream>>>(
        W1a, W1b, W2a, W2b, b1a, b1b, u, tab, bc, b1ap);
    xprep_kernel<<<(N * DN / 8 + 255) / 256, 256, 0, stream>>>(x, xb, N * DN / 8);

    const int P = (N + 1023) / 1024;   // 49 chunks (P <= 64 required)
    hist_kernel<<<(E + 255) / 256, 256, 0, stream>>>(edge_index, counts, E);
    scan1_kernel<<<P, 1024, 0, stream>>>(counts, offsets, partials, N);
    scan3_kernel<<<P, 1024, 0, stream>>>(offsets, partials, cursor, N, E, P);
    scatter_kernel<<<(E + 255) / 256, 256, 0, stream>>>(edge_index, cursor, sorted, E);

    const int eblocks = (E + EPB - 1) / EPB;
    edge_kernel<<<eblocks, 256, 0, stream>>>(
        xb, edge_index, edge_attr, sorted, tab, b1ap, g1, be1, sums, E);

    const int nblocks = (N + NB - 1) / NB;
    node_kernel<<<nblocks, 64, 0, stream>>>(
        xb, sums, offsets, tab, bc, b2a, g2, be2, b2b, out, N);
}